// Round 1
// 571.939 us; speedup vs baseline: 1.6123x; 1.6123x over previous
//
#include <hip/hip_runtime.h>
#include <hip/hip_bf16.h>
#include <stdint.h>

#define TOKENS 2048
#define HIDDEN 2048
#define INTER  1408
#define NEXP   8
#define NPAIR  4096

typedef __attribute__((ext_vector_type(8))) short bf16x8;
typedef __attribute__((ext_vector_type(4))) float f32x4;

static __device__ __forceinline__ unsigned short f2b(float f) {
    union { float f; uint32_t u; } v; v.f = f;
    uint32_t r = (v.u + 0x7FFFu + ((v.u >> 16) & 1u)) >> 16;   // RNE
    return (unsigned short)r;
}

// async global->LDS DMA, 16B per lane. Dest must be linear: base + lane*16.
#define GLDS(SRC, DST) \
    __builtin_amdgcn_global_load_lds( \
        (const __attribute__((address_space(1))) unsigned int*)(SRC), \
        (__attribute__((address_space(3))) unsigned int*)(DST), 16, 0, 0)

// ---------------- routing: pack (token, weight) per expert ----------------
__global__ void route_k(const int* __restrict__ idx, const float* __restrict__ w,
                        int* __restrict__ off, int* __restrict__ tok,
                        float* __restrict__ wgt) {
    __shared__ int cnt[NEXP];
    __shared__ int cur[NEXP];
    int tid = threadIdx.x;
    if (tid < NEXP) cnt[tid] = 0;
    __syncthreads();
    for (int i = tid; i < NPAIR; i += 256) atomicAdd(&cnt[idx[i]], 1);
    __syncthreads();
    if (tid == 0) {
        int s = 0;
        for (int e = 0; e < NEXP; ++e) { off[e] = s; cur[e] = s; s += cnt[e]; }
        off[NEXP] = s;
    }
    __syncthreads();
    for (int i = tid; i < NPAIR; i += 256) {
        int e = idx[i];
        int p = atomicAdd(&cur[e], 1);
        tok[p] = i >> 1;
        wgt[p] = w[i];
    }
}

// ---------------- fp32 -> bf16 bulk convert ----------------
__global__ void conv_k(const float* __restrict__ x, unsigned short* __restrict__ xb, int n) {
    int i = (blockIdx.x * blockDim.x + threadIdx.x) * 4;
    if (i < n) {
        float4 v = *(const float4*)(x + i);
        ushort4 o;
        o.x = f2b(v.x); o.y = f2b(v.y); o.z = f2b(v.z); o.w = f2b(v.w);
        *(ushort4*)(xb + i) = o;
    }
}

// =================== GEMM1: gate+up fused, SwiGLU -> H (bf16) ===================
// m97 structure: global_load_lds width-16 staging into linear (unpadded) LDS,
// double-buffered, 2 barriers/step: stage(b^1,ks+1) -> mfma(b) -> syncthreads.
// DMA latency hides under the MFMA section; barrier drains vmcnt for next step.
// tile 128(M) x 64(N) dual-output (gate & up share the A tile).
__global__ __launch_bounds__(256, 2) void gemm1_k(
    const unsigned short* __restrict__ Xb,
    const unsigned short* __restrict__ Wgb, const unsigned short* __restrict__ Wub,
    const int* __restrict__ off, const int* __restrict__ tok,
    unsigned short* __restrict__ H) {

    const int e    = blockIdx.x;
    const int o0   = off[e];
    const int cnt  = off[e + 1] - o0;
    const int row0 = blockIdx.y * 128;
    if (row0 >= cnt) return;
    const int col0 = blockIdx.z * 64;

    __shared__ __align__(16) unsigned short sA[2][128 * 64];
    __shared__ __align__(16) unsigned short sG[2][64 * 64];
    __shared__ __align__(16) unsigned short sU[2][64 * 64];
    __shared__ int stok[128];

    const int tid = threadIdx.x;
    if (tid < 128) {
        int r = row0 + tid;
        stok[tid] = tok[o0 + (r < cnt ? r : cnt - 1)];
    }
    __syncthreads();

    // segment map: seg s (16B) -> LDS offset s*8 elems, row s>>3, col (s&7)*8.
    // Within a wave s = wbase + lane -> dest is wave-uniform base + lane*16. ✔
    int sa_[4];  const unsigned short* gA[4];
    #pragma unroll
    for (int j = 0; j < 4; ++j) {
        int s = tid + 256 * j, r = s >> 3, c = (s & 7) * 8;
        sa_[j] = s * 8;
        gA[j] = Xb + (size_t)stok[r] * HIDDEN + c;
    }
    int sb_[2];  const unsigned short* gG[2]; const unsigned short* gU[2];
    #pragma unroll
    for (int j = 0; j < 2; ++j) {
        int s = tid + 256 * j, r = s >> 3, c = (s & 7) * 8;
        sb_[j] = s * 8;
        gG[j] = Wgb + ((size_t)e * INTER + col0 + r) * HIDDEN + c;
        gU[j] = Wub + ((size_t)e * INTER + col0 + r) * HIDDEN + c;
    }

    const int wave = tid >> 6, lane = tid & 63;
    const int wm = (wave >> 1) * 64, wn = (wave & 1) * 32;
    const int lm = lane & 15, quad = lane >> 4;

    f32x4 accg[4][2], accu[4][2];
    #pragma unroll
    for (int i = 0; i < 4; ++i)
        #pragma unroll
        for (int j = 0; j < 2; ++j) {
            accg[i][j] = (f32x4){0.f, 0.f, 0.f, 0.f};
            accu[i][j] = (f32x4){0.f, 0.f, 0.f, 0.f};
        }

    // prologue: stage slice 0 into buf 0
    {
        #pragma unroll
        for (int j = 0; j < 4; ++j) GLDS(gA[j], &sA[0][sa_[j]]);
        #pragma unroll
        for (int j = 0; j < 2; ++j) {
            GLDS(gG[j], &sG[0][sb_[j]]);
            GLDS(gU[j], &sU[0][sb_[j]]);
        }
    }
    __syncthreads();

    const int NS = HIDDEN / 64;
    for (int ks = 0; ks < NS; ++ks) {
        const int b = ks & 1;
        if (ks + 1 < NS) {              // issue next-slice DMA before compute
            int ko = (ks + 1) * 64;
            #pragma unroll
            for (int j = 0; j < 4; ++j) GLDS(gA[j] + ko, &sA[b ^ 1][sa_[j]]);
            #pragma unroll
            for (int j = 0; j < 2; ++j) {
                GLDS(gG[j] + ko, &sG[b ^ 1][sb_[j]]);
                GLDS(gU[j] + ko, &sU[b ^ 1][sb_[j]]);
            }
        }
        #pragma unroll
        for (int kk = 0; kk < 64; kk += 32) {
            bf16x8 af[4], gf[2], uf[2];
            #pragma unroll
            for (int mi = 0; mi < 4; ++mi)
                af[mi] = *(const bf16x8*)&sA[b][(wm + mi * 16 + lm) * 64 + kk + quad * 8];
            #pragma unroll
            for (int ni = 0; ni < 2; ++ni) {
                gf[ni] = *(const bf16x8*)&sG[b][(wn + ni * 16 + lm) * 64 + kk + quad * 8];
                uf[ni] = *(const bf16x8*)&sU[b][(wn + ni * 16 + lm) * 64 + kk + quad * 8];
            }
            #pragma unroll
            for (int mi = 0; mi < 4; ++mi)
                #pragma unroll
                for (int ni = 0; ni < 2; ++ni) {
                    accg[mi][ni] = __builtin_amdgcn_mfma_f32_16x16x32_bf16(af[mi], gf[ni], accg[mi][ni], 0, 0, 0);
                    accu[mi][ni] = __builtin_amdgcn_mfma_f32_16x16x32_bf16(af[mi], uf[ni], accu[mi][ni], 0, 0, 0);
                }
        }
        __syncthreads();                // drains vmcnt(0): buf b^1 ready
    }

    #pragma unroll
    for (int mi = 0; mi < 4; ++mi) {
        #pragma unroll
        for (int reg = 0; reg < 4; ++reg) {
            int lr = wm + mi * 16 + quad * 4 + reg;   // C/D: col=lane&15, row=quad*4+reg
            int r  = row0 + lr;
            if (r < cnt) {
                size_t hrow = (size_t)(o0 + r) * INTER;
                #pragma unroll
                for (int ni = 0; ni < 2; ++ni) {
                    float g = accg[mi][ni][reg];
                    float u = accu[mi][ni][reg];
                    float h = g / (1.f + __expf(-g)) * u;
                    H[hrow + col0 + wn + ni * 16 + lm] = f2b(h);
                }
            }
        }
    }
}

// =================== GEMM2: down proj, weighted atomic combine ===================
// Same m97 staging structure. tile 128(M) x 128(N), BK=64.
__global__ __launch_bounds__(256, 2) void gemm2_k(
    const unsigned short* __restrict__ H,
    const unsigned short* __restrict__ Wdb,
    const int* __restrict__ off, const int* __restrict__ tok,
    const float* __restrict__ wgt,
    float* __restrict__ out) {

    const int e    = blockIdx.x;
    const int o0   = off[e];
    const int cnt  = off[e + 1] - o0;
    const int row0 = blockIdx.y * 128;
    if (row0 >= cnt) return;
    const int col0 = blockIdx.z * 128;

    __shared__ __align__(16) unsigned short sA[2][128 * 64];
    __shared__ __align__(16) unsigned short sB[2][128 * 64];
    __shared__ int   stok[128];
    __shared__ float swgt[128];

    const int tid = threadIdx.x;
    if (tid < 128) {
        int r  = row0 + tid;
        int rr = (r < cnt ? r : cnt - 1);
        stok[tid] = tok[o0 + rr];
        swgt[tid] = wgt[o0 + rr];
    }
    __syncthreads();

    int sa_[4];
    const unsigned short* gA[4]; const unsigned short* gB[4];
    #pragma unroll
    for (int j = 0; j < 4; ++j) {
        int s = tid + 256 * j, r = s >> 3, c = (s & 7) * 8;
        sa_[j] = s * 8;
        int gr = row0 + r; if (gr >= cnt) gr = cnt - 1;
        gA[j] = H + (size_t)(o0 + gr) * INTER + c;
        gB[j] = Wdb + ((size_t)e * HIDDEN + col0 + r) * INTER + c;
    }

    const int wave = tid >> 6, lane = tid & 63;
    const int wm = (wave >> 1) * 64, wn = (wave & 1) * 64;
    const int lm = lane & 15, quad = lane >> 4;

    f32x4 acc[4][4];
    #pragma unroll
    for (int i = 0; i < 4; ++i)
        #pragma unroll
        for (int j = 0; j < 4; ++j) acc[i][j] = (f32x4){0.f, 0.f, 0.f, 0.f};

    // prologue
    #pragma unroll
    for (int j = 0; j < 4; ++j) {
        GLDS(gA[j], &sA[0][sa_[j]]);
        GLDS(gB[j], &sB[0][sa_[j]]);
    }
    __syncthreads();

    const int NS = INTER / 64;
    for (int ks = 0; ks < NS; ++ks) {
        const int b = ks & 1;
        if (ks + 1 < NS) {
            int ko = (ks + 1) * 64;
            #pragma unroll
            for (int j = 0; j < 4; ++j) {
                GLDS(gA[j] + ko, &sA[b ^ 1][sa_[j]]);
                GLDS(gB[j] + ko, &sB[b ^ 1][sa_[j]]);
            }
        }
        #pragma unroll
        for (int kk = 0; kk < 64; kk += 32) {
            bf16x8 af[4], bf[4];
            #pragma unroll
            for (int mi = 0; mi < 4; ++mi)
                af[mi] = *(const bf16x8*)&sA[b][(wm + mi * 16 + lm) * 64 + kk + quad * 8];
            #pragma unroll
            for (int ni = 0; ni < 4; ++ni)
                bf[ni] = *(const bf16x8*)&sB[b][(wn + ni * 16 + lm) * 64 + kk + quad * 8];
            #pragma unroll
            for (int mi = 0; mi < 4; ++mi)
                #pragma unroll
                for (int ni = 0; ni < 4; ++ni)
                    acc[mi][ni] = __builtin_amdgcn_mfma_f32_16x16x32_bf16(af[mi], bf[ni], acc[mi][ni], 0, 0, 0);
        }
        __syncthreads();
    }

    #pragma unroll
    for (int mi = 0; mi < 4; ++mi) {
        #pragma unroll
        for (int reg = 0; reg < 4; ++reg) {
            int lr = wm + mi * 16 + quad * 4 + reg;
            int r  = row0 + lr;
            if (r < cnt) {
                int   t = stok[lr];
                float w = swgt[lr];
                #pragma unroll
                for (int ni = 0; ni < 4; ++ni)
                    atomicAdd(&out[(size_t)t * HIDDEN + col0 + wn + ni * 16 + lm],
                              w * acc[mi][ni][reg]);
            }
        }
    }
}

extern "C" void kernel_launch(void* const* d_in, const int* in_sizes, int n_in,
                              void* d_out, int out_size, void* d_ws, size_t ws_size,
                              hipStream_t stream) {
    const float* X   = (const float*)d_in[0];
    const int*   idx = (const int*)d_in[1];
    const float* tw  = (const float*)d_in[2];
    const float* Wg  = (const float*)d_in[3];
    const float* Wu  = (const float*)d_in[4];
    const float* Wd  = (const float*)d_in[5];
    float* out = (float*)d_out;

    char* ws = (char*)d_ws;
    const size_t OFF_TOK = 64;
    const size_t OFF_WGT = 64 + (size_t)NPAIR * 4;
    const size_t OFF_XB  = 65536;
    const size_t OFF_H   = OFF_XB + (size_t)TOKENS * HIDDEN * 2;           // 8 MB Xb
    const size_t WELEMS  = (size_t)NEXP * INTER * HIDDEN;                  // 23.07M
    const size_t OFF_WG  = OFF_H + (size_t)NPAIR * INTER * 2;              // 11.5 MB H
    const size_t OFF_WU  = OFF_WG + WELEMS * 2;
    const size_t OFF_WD  = OFF_WU + WELEMS * 2;

    int*            off = (int*)ws;
    int*            tok = (int*)(ws + OFF_TOK);
    float*          wgt = (float*)(ws + OFF_WGT);
    unsigned short* Xb  = (unsigned short*)(ws + OFF_XB);
    unsigned short* H   = (unsigned short*)(ws + OFF_H);
    unsigned short* Wgb = (unsigned short*)(ws + OFF_WG);
    unsigned short* Wub = (unsigned short*)(ws + OFF_WU);
    unsigned short* Wdb = (unsigned short*)(ws + OFF_WD);

    hipMemsetAsync(d_out, 0, (size_t)out_size * sizeof(float), stream);

    route_k<<<1, 256, 0, stream>>>(idx, tw, off, tok, wgt);
    conv_k<<<(TOKENS * HIDDEN / 4 + 255) / 256, 256, 0, stream>>>(X, Xb, TOKENS * HIDDEN);

    const int wn4 = (int)(WELEMS / 4);
    conv_k<<<(wn4 + 255) / 256, 256, 0, stream>>>(Wg, Wgb, (int)WELEMS);
    conv_k<<<(wn4 + 255) / 256, 256, 0, stream>>>(Wu, Wub, (int)WELEMS);
    conv_k<<<(wn4 + 255) / 256, 256, 0, stream>>>(Wd, Wdb, (int)WELEMS);

    // x = expert: consecutive block IDs spread experts across XCDs (id%8 heuristic),
    // giving each XCD one expert's X/W stream (fits 4 MB L2).
    gemm1_k<<<dim3(NEXP, NPAIR / 128, INTER / 64), 256, 0, stream>>>(Xb, Wgb, Wub, off, tok, H);
    gemm2_k<<<dim3(NEXP, NPAIR / 128, HIDDEN / 128), 256, 0, stream>>>(H, Wdb, off, tok, wgt, out);
}

// Round 2
// 476.019 us; speedup vs baseline: 1.9372x; 1.2015x over previous
//
#include <hip/hip_runtime.h>
#include <hip/hip_bf16.h>
#include <stdint.h>

#define TOKENS 2048
#define HIDDEN 2048
#define INTER  1408
#define NEXP   8
#define NPAIR  4096

typedef __attribute__((ext_vector_type(8))) short bf16x8;
typedef __attribute__((ext_vector_type(4))) float f32x4;

static __device__ __forceinline__ unsigned short f2b(float f) {
    union { float f; uint32_t u; } v; v.f = f;
    uint32_t r = (v.u + 0x7FFFu + ((v.u >> 16) & 1u)) >> 16;   // RNE
    return (unsigned short)r;
}

// async global->LDS DMA, 16B per lane. Dest must be linear: base + lane*16.
#define GLDS(SRC, DST) \
    __builtin_amdgcn_global_load_lds( \
        (const __attribute__((address_space(1))) unsigned int*)(SRC), \
        (__attribute__((address_space(3))) unsigned int*)(DST), 16, 0, 0)

// ---------------- routing: pack (token, weight) per expert ----------------
__global__ void route_k(const int* __restrict__ idx, const float* __restrict__ w,
                        int* __restrict__ off, int* __restrict__ tok,
                        float* __restrict__ wgt) {
    __shared__ int cnt[NEXP];
    __shared__ int cur[NEXP];
    int tid = threadIdx.x;
    if (tid < NEXP) cnt[tid] = 0;
    __syncthreads();
    for (int i = tid; i < NPAIR; i += 256) atomicAdd(&cnt[idx[i]], 1);
    __syncthreads();
    if (tid == 0) {
        int s = 0;
        for (int e = 0; e < NEXP; ++e) { off[e] = s; cur[e] = s; s += cnt[e]; }
        off[NEXP] = s;
    }
    __syncthreads();
    for (int i = tid; i < NPAIR; i += 256) {
        int e = idx[i];
        int p = atomicAdd(&cur[e], 1);
        tok[p] = i >> 1;
        wgt[p] = w[i];
    }
}

// ---------------- fp32 -> bf16 bulk convert ----------------
__global__ void conv_k(const float* __restrict__ x, unsigned short* __restrict__ xb, int n) {
    int i = (blockIdx.x * blockDim.x + threadIdx.x) * 4;
    if (i < n) {
        float4 v = *(const float4*)(x + i);
        ushort4 o;
        o.x = f2b(v.x); o.y = f2b(v.y); o.z = f2b(v.z); o.w = f2b(v.w);
        *(ushort4*)(xb + i) = o;
    }
}

// LDS row = 32 bf16 elems (64B), 4 slots of 8 elems. Source col pre-swizzled
// (slot q ^= (row>>1)&3) so the linear GLDS write produces a swizzled layout;
// reads XOR the same bits (rule #21: same involution on both sides).
// Quarter-wave ds_read_b128 then spreads 16 lanes over 16 banks (~minimal).

// =================== GEMM1: gate+up fused, SwiGLU -> H (bf16) ===================
// tile 128(M) x 64(N) dual-output, BK=32, double-buffered, 33KB LDS -> 4 blk/CU.
__global__ __launch_bounds__(256, 4) void gemm1_k(
    const unsigned short* __restrict__ Xb,
    const unsigned short* __restrict__ Wgb, const unsigned short* __restrict__ Wub,
    const int* __restrict__ off, const int* __restrict__ tok,
    unsigned short* __restrict__ H) {

    const int e    = blockIdx.x;
    const int o0   = off[e];
    const int cnt  = off[e + 1] - o0;
    const int row0 = blockIdx.y * 128;
    if (row0 >= cnt) return;
    const int col0 = blockIdx.z * 64;

    __shared__ __align__(16) unsigned short sA[2][128 * 32];
    __shared__ __align__(16) unsigned short sG[2][64 * 32];
    __shared__ __align__(16) unsigned short sU[2][64 * 32];
    __shared__ int stok[128];

    const int tid = threadIdx.x;
    if (tid < 128) {
        int r = row0 + tid;
        stok[tid] = tok[o0 + (r < cnt ? r : cnt - 1)];
    }
    __syncthreads();

    // A: 2 segs/thread. seg s: LDS row r=s>>2, slot q=s&3, dest linear s*16B.
    int sa_[2]; const unsigned short* gA[2];
    #pragma unroll
    for (int j = 0; j < 2; ++j) {
        int s = tid + 256 * j, r = s >> 2, q = s & 3;
        sa_[j] = s * 8;
        gA[j] = Xb + (size_t)stok[r] * HIDDEN + ((q ^ ((r >> 1) & 3)) << 3);
    }
    // G,U: 1 seg/thread (64 rows x 32).
    int sb_; const unsigned short* gG; const unsigned short* gU;
    {
        int s = tid, r = s >> 2, q = s & 3;
        sb_ = s * 8;
        int c = (q ^ ((r >> 1) & 3)) << 3;
        gG = Wgb + ((size_t)e * INTER + col0 + r) * HIDDEN + c;
        gU = Wub + ((size_t)e * INTER + col0 + r) * HIDDEN + c;
    }

    const int wave = tid >> 6, lane = tid & 63;
    const int wm = (wave >> 1) * 64, wn = (wave & 1) * 32;
    const int lm = lane & 15, quad = lane >> 4;
    const int swz = ((quad ^ ((lane >> 1) & 3)) << 3);   // read-side XOR (elems)

    f32x4 accg[4][2], accu[4][2];
    #pragma unroll
    for (int i = 0; i < 4; ++i)
        #pragma unroll
        for (int j = 0; j < 2; ++j) {
            accg[i][j] = (f32x4){0.f, 0.f, 0.f, 0.f};
            accu[i][j] = (f32x4){0.f, 0.f, 0.f, 0.f};
        }

    // prologue: stage slice 0 into buf 0
    GLDS(gA[0], &sA[0][sa_[0]]);
    GLDS(gA[1], &sA[0][sa_[1]]);
    GLDS(gG, &sG[0][sb_]);
    GLDS(gU, &sU[0][sb_]);
    __syncthreads();

    const int NS = HIDDEN / 32;
    for (int ks = 0; ks < NS; ++ks) {
        const int b = ks & 1;
        if (ks + 1 < NS) {              // issue next-slice DMA before compute
            const int ko = (ks + 1) * 32;
            GLDS(gA[0] + ko, &sA[b ^ 1][sa_[0]]);
            GLDS(gA[1] + ko, &sA[b ^ 1][sa_[1]]);
            GLDS(gG + ko, &sG[b ^ 1][sb_]);
            GLDS(gU + ko, &sU[b ^ 1][sb_]);
        }
        bf16x8 af[4], gf[2], uf[2];
        #pragma unroll
        for (int mi = 0; mi < 4; ++mi)
            af[mi] = *(const bf16x8*)&sA[b][(wm + mi * 16 + lm) * 32 + swz];
        #pragma unroll
        for (int ni = 0; ni < 2; ++ni) {
            gf[ni] = *(const bf16x8*)&sG[b][(wn + ni * 16 + lm) * 32 + swz];
            uf[ni] = *(const bf16x8*)&sU[b][(wn + ni * 16 + lm) * 32 + swz];
        }
        #pragma unroll
        for (int mi = 0; mi < 4; ++mi)
            #pragma unroll
            for (int ni = 0; ni < 2; ++ni) {
                accg[mi][ni] = __builtin_amdgcn_mfma_f32_16x16x32_bf16(af[mi], gf[ni], accg[mi][ni], 0, 0, 0);
                accu[mi][ni] = __builtin_amdgcn_mfma_f32_16x16x32_bf16(af[mi], uf[ni], accu[mi][ni], 0, 0, 0);
            }
        __syncthreads();                // drains vmcnt(0): buf b^1 ready
    }

    #pragma unroll
    for (int mi = 0; mi < 4; ++mi) {
        #pragma unroll
        for (int reg = 0; reg < 4; ++reg) {
            int lr = wm + mi * 16 + quad * 4 + reg;   // C/D: col=lane&15, row=quad*4+reg
            int r  = row0 + lr;
            if (r < cnt) {
                size_t hrow = (size_t)(o0 + r) * INTER;
                #pragma unroll
                for (int ni = 0; ni < 2; ++ni) {
                    float g = accg[mi][ni][reg];
                    float u = accu[mi][ni][reg];
                    float h = g / (1.f + __expf(-g)) * u;
                    H[hrow + col0 + wn + ni * 16 + lm] = f2b(h);
                }
            }
        }
    }
}

// =================== GEMM2: down proj, weighted atomic combine ===================
// tile 128(M) x 128(N), BK=32, 33KB LDS -> 4 blk/CU.
__global__ __launch_bounds__(256, 4) void gemm2_k(
    const unsigned short* __restrict__ H,
    const unsigned short* __restrict__ Wdb,
    const int* __restrict__ off, const int* __restrict__ tok,
    const float* __restrict__ wgt,
    float* __restrict__ out) {

    const int e    = blockIdx.x;
    const int o0   = off[e];
    const int cnt  = off[e + 1] - o0;
    const int row0 = blockIdx.y * 128;
    if (row0 >= cnt) return;
    const int col0 = blockIdx.z * 128;

    __shared__ __align__(16) unsigned short sA[2][128 * 32];
    __shared__ __align__(16) unsigned short sB[2][128 * 32];
    __shared__ int   stok[128];
    __shared__ float swgt[128];

    const int tid = threadIdx.x;
    if (tid < 128) {
        int r  = row0 + tid;
        int rr = (r < cnt ? r : cnt - 1);
        stok[tid] = tok[o0 + rr];
        swgt[tid] = wgt[o0 + rr];
    }
    __syncthreads();

    int sa_[2];
    const unsigned short* gA[2]; const unsigned short* gB[2];
    #pragma unroll
    for (int j = 0; j < 2; ++j) {
        int s = tid + 256 * j, r = s >> 2, q = s & 3;
        sa_[j] = s * 8;
        int c = (q ^ ((r >> 1) & 3)) << 3;
        int gr = row0 + r; if (gr >= cnt) gr = cnt - 1;
        gA[j] = H + (size_t)(o0 + gr) * INTER + c;
        gB[j] = Wdb + ((size_t)e * HIDDEN + col0 + r) * INTER + c;
    }

    const int wave = tid >> 6, lane = tid & 63;
    const int wm = (wave >> 1) * 64, wn = (wave & 1) * 64;
    const int lm = lane & 15, quad = lane >> 4;
    const int swz = ((quad ^ ((lane >> 1) & 3)) << 3);

    f32x4 acc[4][4];
    #pragma unroll
    for (int i = 0; i < 4; ++i)
        #pragma unroll
        for (int j = 0; j < 4; ++j) acc[i][j] = (f32x4){0.f, 0.f, 0.f, 0.f};

    // prologue
    #pragma unroll
    for (int j = 0; j < 2; ++j) {
        GLDS(gA[j], &sA[0][sa_[j]]);
        GLDS(gB[j], &sB[0][sa_[j]]);
    }
    __syncthreads();

    const int NS = INTER / 32;
    for (int ks = 0; ks < NS; ++ks) {
        const int b = ks & 1;
        if (ks + 1 < NS) {
            const int ko = (ks + 1) * 32;
            #pragma unroll
            for (int j = 0; j < 2; ++j) {
                GLDS(gA[j] + ko, &sA[b ^ 1][sa_[j]]);
                GLDS(gB[j] + ko, &sB[b ^ 1][sa_[j]]);
            }
        }
        bf16x8 af[4], bf[4];
        #pragma unroll
        for (int mi = 0; mi < 4; ++mi)
            af[mi] = *(const bf16x8*)&sA[b][(wm + mi * 16 + lm) * 32 + swz];
        #pragma unroll
        for (int ni = 0; ni < 4; ++ni)
            bf[ni] = *(const bf16x8*)&sB[b][(wn + ni * 16 + lm) * 32 + swz];
        #pragma unroll
        for (int mi = 0; mi < 4; ++mi)
            #pragma unroll
            for (int ni = 0; ni < 4; ++ni)
                acc[mi][ni] = __builtin_amdgcn_mfma_f32_16x16x32_bf16(af[mi], bf[ni], acc[mi][ni], 0, 0, 0);
        __syncthreads();
    }

    #pragma unroll
    for (int mi = 0; mi < 4; ++mi) {
        #pragma unroll
        for (int reg = 0; reg < 4; ++reg) {
            int lr = wm + mi * 16 + quad * 4 + reg;
            int r  = row0 + lr;
            if (r < cnt) {
                int   t = stok[lr];
                float w = swgt[lr];
                #pragma unroll
                for (int ni = 0; ni < 4; ++ni)
                    atomicAdd(&out[(size_t)t * HIDDEN + col0 + wn + ni * 16 + lm],
                              w * acc[mi][ni][reg]);
            }
        }
    }
}

extern "C" void kernel_launch(void* const* d_in, const int* in_sizes, int n_in,
                              void* d_out, int out_size, void* d_ws, size_t ws_size,
                              hipStream_t stream) {
    const float* X   = (const float*)d_in[0];
    const int*   idx = (const int*)d_in[1];
    const float* tw  = (const float*)d_in[2];
    const float* Wg  = (const float*)d_in[3];
    const float* Wu  = (const float*)d_in[4];
    const float* Wd  = (const float*)d_in[5];
    float* out = (float*)d_out;

    char* ws = (char*)d_ws;
    const size_t OFF_TOK = 64;
    const size_t OFF_WGT = 64 + (size_t)NPAIR * 4;
    const size_t OFF_XB  = 65536;
    const size_t OFF_H   = OFF_XB + (size_t)TOKENS * HIDDEN * 2;           // 8 MB Xb
    const size_t WELEMS  = (size_t)NEXP * INTER * HIDDEN;                  // 23.07M
    const size_t OFF_WG  = OFF_H + (size_t)NPAIR * INTER * 2;              // 11.5 MB H
    const size_t OFF_WU  = OFF_WG + WELEMS * 2;
    const size_t OFF_WD  = OFF_WU + WELEMS * 2;

    int*            off = (int*)ws;
    int*            tok = (int*)(ws + OFF_TOK);
    float*          wgt = (float*)(ws + OFF_WGT);
    unsigned short* Xb  = (unsigned short*)(ws + OFF_XB);
    unsigned short* H   = (unsigned short*)(ws + OFF_H);
    unsigned short* Wgb = (unsigned short*)(ws + OFF_WG);
    unsigned short* Wub = (unsigned short*)(ws + OFF_WU);
    unsigned short* Wdb = (unsigned short*)(ws + OFF_WD);

    hipMemsetAsync(d_out, 0, (size_t)out_size * sizeof(float), stream);

    route_k<<<1, 256, 0, stream>>>(idx, tw, off, tok, wgt);
    conv_k<<<(TOKENS * HIDDEN / 4 + 255) / 256, 256, 0, stream>>>(X, Xb, TOKENS * HIDDEN);

    const int wn4 = (int)(WELEMS / 4);
    conv_k<<<(wn4 + 255) / 256, 256, 0, stream>>>(Wg, Wgb, (int)WELEMS);
    conv_k<<<(wn4 + 255) / 256, 256, 0, stream>>>(Wu, Wub, (int)WELEMS);
    conv_k<<<(wn4 + 255) / 256, 256, 0, stream>>>(Wd, Wdb, (int)WELEMS);

    // x = expert: consecutive block IDs spread experts across XCDs (id%8 heuristic);
    // expert's X-tile slice (~2 MB) stays L2-resident on its XCD.
    gemm1_k<<<dim3(NEXP, NPAIR / 128, INTER / 64), 256, 0, stream>>>(Xb, Wgb, Wub, off, tok, H);
    gemm2_k<<<dim3(NEXP, NPAIR / 128, HIDDEN / 128), 256, 0, stream>>>(H, Wdb, off, tok, wgt, out);
}